// Round 2
// baseline (149.419 us; speedup 1.0000x reference)
//
#include <hip/hip_runtime.h>
#include <math.h>

// Deformation4D: N=1M gaussians, K_NB=10 neighbors, K_TOTAL=300 control points.
//
// v3: single dispatch (the v2 separate build kernel serialized ~5-10us of
// launch latency ahead of the main kernel and canceled the LDS win).
// - fused in-block table build: per CP {q_hat(16B), b(16B)}, b = p + t - R*p,
//   interleaved at s4[2cp], s4[2cp+1] (one addr calc, offset:16 second read).
// - monomial algebra: sum_k w_k R(q_hat_k) is linear in M = sum w q q^T, so we
//   gather only q_hat+b (32B/neighbor, 2x ds_read_b128) and rebuild sum(wR)
//   in the epilogue.
// - 2 gaussians per thread: index/weight rows for a pair are 80B and 16B
//   aligned -> 5x int4 + 5x float4 loads replace 40 scalar loads; means and
//   out_means move as float2; quats/out_quats as float4.

__device__ __forceinline__ void compute_cp(
    const float* __restrict__ ctrl_trans,
    const float* __restrict__ ctrl_rot,
    const float* __restrict__ ctrl_pos,
    int cp, float4* q_out, float4* b_out)
{
    float qw = ctrl_rot[cp * 4 + 0];
    float qx = ctrl_rot[cp * 4 + 1];
    float qy = ctrl_rot[cp * 4 + 2];
    float qz = ctrl_rot[cp * 4 + 3];
    float n   = sqrtf(qw * qw + qx * qx + qy * qy + qz * qz);
    float inv = 1.0f / fmaxf(n, 1e-8f);
    float w = qw * inv, x = qx * inv, y = qy * inv, z = qz * inv;
    float R00 = 1.0f - 2.0f * (y * y + z * z);
    float R01 = 2.0f * (x * y - w * z);
    float R02 = 2.0f * (x * z + w * y);
    float R10 = 2.0f * (x * y + w * z);
    float R11 = 1.0f - 2.0f * (x * x + z * z);
    float R12 = 2.0f * (y * z - w * x);
    float R20 = 2.0f * (x * z - w * y);
    float R21 = 2.0f * (y * z + w * x);
    float R22 = 1.0f - 2.0f * (x * x + y * y);
    float px = ctrl_pos[cp * 3 + 0];
    float py = ctrl_pos[cp * 3 + 1];
    float pz = ctrl_pos[cp * 3 + 2];
    float tx = ctrl_trans[cp * 3 + 0];
    float ty = ctrl_trans[cp * 3 + 1];
    float tz = ctrl_trans[cp * 3 + 2];
    *q_out = make_float4(w, x, y, z);
    *b_out = make_float4(px + tx - (R00 * px + R01 * py + R02 * pz),
                         py + ty - (R10 * px + R11 * py + R12 * pz),
                         pz + tz - (R20 * px + R21 * py + R22 * pz),
                         0.0f);
}

struct Accum {
    float W;
    float Mxx, Myy, Mzz, Mxy, Mxz, Myz, Mwx, Mwy, Mwz;
    float qsw, qsx, qsy, qsz;
    float bsx, bsy, bsz;
};

__device__ __forceinline__ void acc_init(Accum& a) {
    a.W = 0.0f;
    a.Mxx = a.Myy = a.Mzz = 0.0f;
    a.Mxy = a.Mxz = a.Myz = 0.0f;
    a.Mwx = a.Mwy = a.Mwz = 0.0f;
    a.qsw = a.qsx = a.qsy = a.qsz = 0.0f;
    a.bsx = a.bsy = a.bsz = 0.0f;
}

__device__ __forceinline__ void acc_neighbor(Accum& a, const float4* __restrict__ s4,
                                             int cp, float w) {
    float4 q = s4[2 * cp];        // (w,x,y,z) normalized
    float4 b = s4[2 * cp + 1];    // (bx,by,bz,_)
    float tw = w * q.x, tx = w * q.y, ty = w * q.z, tz = w * q.w;
    a.W += w;
    a.Mxx = fmaf(tx, q.y, a.Mxx);
    a.Myy = fmaf(ty, q.z, a.Myy);
    a.Mzz = fmaf(tz, q.w, a.Mzz);
    a.Mxy = fmaf(tx, q.z, a.Mxy);
    a.Mxz = fmaf(tx, q.w, a.Mxz);
    a.Myz = fmaf(ty, q.w, a.Myz);
    a.Mwx = fmaf(tw, q.y, a.Mwx);
    a.Mwy = fmaf(tw, q.z, a.Mwy);
    a.Mwz = fmaf(tw, q.w, a.Mwz);
    a.qsw += tw; a.qsx += tx; a.qsy += ty; a.qsz += tz;
    a.bsx = fmaf(w, b.x, a.bsx);
    a.bsy = fmaf(w, b.y, a.bsy);
    a.bsz = fmaf(w, b.z, a.bsz);
}

// epilogue: dm = (sum wR) * mean + sum w b ; oq = normalize(sum w q) * gq
__device__ __forceinline__ void acc_epilogue(const Accum& a,
                                             float mx, float my, float mz,
                                             float4 g,
                                             float* dmx, float* dmy, float* dmz,
                                             float4* oq) {
    float A00 = a.W - 2.0f * (a.Myy + a.Mzz);
    float A01 = 2.0f * (a.Mxy - a.Mwz);
    float A02 = 2.0f * (a.Mxz + a.Mwy);
    float A10 = 2.0f * (a.Mxy + a.Mwz);
    float A11 = a.W - 2.0f * (a.Mxx + a.Mzz);
    float A12 = 2.0f * (a.Myz - a.Mwx);
    float A20 = 2.0f * (a.Mxz - a.Mwy);
    float A21 = 2.0f * (a.Myz + a.Mwx);
    float A22 = a.W - 2.0f * (a.Mxx + a.Myy);

    *dmx = fmaf(A00, mx, fmaf(A01, my, fmaf(A02, mz, a.bsx)));
    *dmy = fmaf(A10, mx, fmaf(A11, my, fmaf(A12, mz, a.bsy)));
    *dmz = fmaf(A20, mx, fmaf(A21, my, fmaf(A22, mz, a.bsz)));

    float n   = sqrtf(a.qsw * a.qsw + a.qsx * a.qsx + a.qsy * a.qsy + a.qsz * a.qsz);
    float inv = 1.0f / fmaxf(n, 1e-8f);
    float bw = a.qsw * inv, bx = a.qsx * inv, by = a.qsy * inv, bz = a.qsz * inv;

    float gw = g.x, gx = g.y, gy = g.z, gz = g.w;
    oq->x = bw * gw - bx * gx - by * gy - bz * gz;
    oq->y = bw * gx + bx * gw + by * gz - bz * gy;
    oq->z = bw * gy - bx * gz + by * gw + bz * gx;
    oq->w = bw * gz + bx * gy - by * gx + bz * gw;
}

// Fast path: KNB=10 fixed, 2 gaussians per thread, vectorized idx/weight loads.
__global__ __launch_bounds__(256) void deform_pair_kernel(
    const float* __restrict__ means,
    const float* __restrict__ quats,
    const float* __restrict__ weights,
    const float* __restrict__ ctrl_trans,
    const float* __restrict__ ctrl_rot,
    const float* __restrict__ ctrl_pos,
    const int*   __restrict__ indices,
    float* __restrict__ out_means,
    float* __restrict__ out_quats,
    int N, int K_TOTAL)
{
    extern __shared__ float4 s4[];
    for (int cp = threadIdx.x; cp < K_TOTAL; cp += blockDim.x) {
        float4 q, b;
        compute_cp(ctrl_trans, ctrl_rot, ctrl_pos, cp, &q, &b);
        s4[2 * cp]     = q;
        s4[2 * cp + 1] = b;
    }
    __syncthreads();

    long long tid = (long long)blockIdx.x * blockDim.x + threadIdx.x;
    long long i0  = 2 * tid;
    if (i0 >= N) return;

    if (i0 + 1 < N) {
        // ---- pair fast path: 80B idx row + 80B weight row, 16B-aligned ----
        const int4*   ip = (const int4*)(indices + i0 * 10);
        const float4* wp = (const float4*)(weights + i0 * 10);
        int4   I0 = ip[0], I1 = ip[1], I2 = ip[2], I3 = ip[3], I4 = ip[4];
        float4 W0 = wp[0], W1 = wp[1], W2 = wp[2], W3 = wp[3], W4 = wp[4];

        Accum a0; acc_init(a0);
        acc_neighbor(a0, s4, I0.x, W0.x);
        acc_neighbor(a0, s4, I0.y, W0.y);
        acc_neighbor(a0, s4, I0.z, W0.z);
        acc_neighbor(a0, s4, I0.w, W0.w);
        acc_neighbor(a0, s4, I1.x, W1.x);
        acc_neighbor(a0, s4, I1.y, W1.y);
        acc_neighbor(a0, s4, I1.z, W1.z);
        acc_neighbor(a0, s4, I1.w, W1.w);
        acc_neighbor(a0, s4, I2.x, W2.x);
        acc_neighbor(a0, s4, I2.y, W2.y);

        Accum a1; acc_init(a1);
        acc_neighbor(a1, s4, I2.z, W2.z);
        acc_neighbor(a1, s4, I2.w, W2.w);
        acc_neighbor(a1, s4, I3.x, W3.x);
        acc_neighbor(a1, s4, I3.y, W3.y);
        acc_neighbor(a1, s4, I3.z, W3.z);
        acc_neighbor(a1, s4, I3.w, W3.w);
        acc_neighbor(a1, s4, I4.x, W4.x);
        acc_neighbor(a1, s4, I4.y, W4.y);
        acc_neighbor(a1, s4, I4.z, W4.z);
        acc_neighbor(a1, s4, I4.w, W4.w);

        // means for the pair: 24B, 8B-aligned -> 3x float2
        const float2* mp = (const float2*)(means + i0 * 3);
        float2 m01 = mp[0], m23 = mp[1], m45 = mp[2];

        float4 g0 = ((const float4*)quats)[i0];
        float4 g1 = ((const float4*)quats)[i0 + 1];

        float d0x, d0y, d0z, d1x, d1y, d1z;
        float4 oq0, oq1;
        acc_epilogue(a0, m01.x, m01.y, m23.x, g0, &d0x, &d0y, &d0z, &oq0);
        acc_epilogue(a1, m23.y, m45.x, m45.y, g1, &d1x, &d1y, &d1z, &oq1);

        float2* omp = (float2*)(out_means + i0 * 3);
        omp[0] = make_float2(d0x, d0y);
        omp[1] = make_float2(d0z, d1x);
        omp[2] = make_float2(d1y, d1z);

        float4* oqp = (float4*)(out_quats + i0 * 4);
        oqp[0] = oq0;
        oqp[1] = oq1;
    } else {
        // ---- tail: single gaussian, scalar loads ----
        const int*   idx_row = indices + i0 * 10;
        const float* w_row   = weights + i0 * 10;
        Accum a0; acc_init(a0);
#pragma unroll
        for (int k = 0; k < 10; k++)
            acc_neighbor(a0, s4, idx_row[k], w_row[k]);

        float mx = means[i0 * 3 + 0];
        float my = means[i0 * 3 + 1];
        float mz = means[i0 * 3 + 2];
        float4 g0 = ((const float4*)quats)[i0];
        float dx, dy, dz;
        float4 oq0;
        acc_epilogue(a0, mx, my, mz, g0, &dx, &dy, &dz, &oq0);
        out_means[i0 * 3 + 0] = dx;
        out_means[i0 * 3 + 1] = dy;
        out_means[i0 * 3 + 2] = dz;
        ((float4*)out_quats)[i0] = oq0;
    }
}

// Generic fallback: runtime K_NB, 1 gaussian per thread, fused table build.
__global__ __launch_bounds__(256) void deform_generic_kernel(
    const float* __restrict__ means,
    const float* __restrict__ quats,
    const float* __restrict__ weights,
    const float* __restrict__ ctrl_trans,
    const float* __restrict__ ctrl_rot,
    const float* __restrict__ ctrl_pos,
    const int*   __restrict__ indices,
    float* __restrict__ out_means,
    float* __restrict__ out_quats,
    int N, int K_NB, int K_TOTAL)
{
    extern __shared__ float4 s4[];
    for (int cp = threadIdx.x; cp < K_TOTAL; cp += blockDim.x) {
        float4 q, b;
        compute_cp(ctrl_trans, ctrl_rot, ctrl_pos, cp, &q, &b);
        s4[2 * cp]     = q;
        s4[2 * cp + 1] = b;
    }
    __syncthreads();

    long long i = (long long)blockIdx.x * blockDim.x + threadIdx.x;
    if (i >= N) return;

    const int*   idx_row = indices + i * K_NB;
    const float* w_row   = weights + i * K_NB;
    Accum a0; acc_init(a0);
    for (int k = 0; k < K_NB; k++)
        acc_neighbor(a0, s4, idx_row[k], w_row[k]);

    float mx = means[i * 3 + 0];
    float my = means[i * 3 + 1];
    float mz = means[i * 3 + 2];
    float4 g0 = ((const float4*)quats)[i];
    float dx, dy, dz;
    float4 oq0;
    acc_epilogue(a0, mx, my, mz, g0, &dx, &dy, &dz, &oq0);
    out_means[i * 3 + 0] = dx;
    out_means[i * 3 + 1] = dy;
    out_means[i * 3 + 2] = dz;
    ((float4*)out_quats)[i] = oq0;
}

extern "C" void kernel_launch(void* const* d_in, const int* in_sizes, int n_in,
                              void* d_out, int out_size, void* d_ws, size_t ws_size,
                              hipStream_t stream) {
    const float* means      = (const float*)d_in[0];
    const float* quats      = (const float*)d_in[1];
    const float* weights    = (const float*)d_in[2];
    const float* ctrl_trans = (const float*)d_in[3];
    const float* ctrl_rot   = (const float*)d_in[4];
    const float* ctrl_pos   = (const float*)d_in[5];
    const int*   indices    = (const int*)d_in[6];

    int N       = in_sizes[0] / 3;
    int K_NB    = in_sizes[2] / N;       // weights is N*K_NB
    int K_TOTAL = in_sizes[3] / 3;       // ctrl_translations is K_TOTAL*3

    float* out_means = (float*)d_out;
    float* out_quats = (float*)d_out + (long long)N * 3;

    int block = 256;
    size_t smem = (size_t)K_TOTAL * 2 * sizeof(float4);

    if (K_NB == 10) {
        long long pairs = ((long long)N + 1) / 2;
        int grid = (int)((pairs + block - 1) / block);
        deform_pair_kernel<<<grid, block, smem, stream>>>(
            means, quats, weights, ctrl_trans, ctrl_rot, ctrl_pos, indices,
            out_means, out_quats, N, K_TOTAL);
    } else {
        int grid = (int)(((long long)N + block - 1) / block);
        deform_generic_kernel<<<grid, block, smem, stream>>>(
            means, quats, weights, ctrl_trans, ctrl_rot, ctrl_pos, indices,
            out_means, out_quats, N, K_NB, K_TOTAL);
    }
}